// Round 4
// baseline (348.527 us; speedup 1.0000x reference)
//
#include <hip/hip_runtime.h>
#include <math.h>

// MultiLocalCosineLinear: B=65536 rows, D=768, C=100, P=4950 pairs.
// out layout (all float32): [0..B)  = preds (class id as float)
//                           [B..3B) = logits, row-major (B,2)
//
// R10 = R9 + bijective XCD-chunk swizzle on the MAIN kernel only.
// R9 post-mortem: grouping gave ~0 on main because same-pair waves were
// round-robined across 8 non-coherent XCD L2s — every XCD re-pulled every
// tile from L3 (~372 MB at ~4.5 TB/s = the whole gap). Swizzle
// L=(bid&7)*CPX+(bid>>3) gives each XCD a contiguous pair-sorted slice, so
// each 6KB tile lives in exactly ~1 XCD L2 and its ~13 re-reads run at L2
// speed. All math byte-identical to R9 (passed, absmax 2.44e-4).

#define D_DIM 768
#define C_DIM 100
#define EPS_N 1e-12

typedef float vf4 __attribute__((ext_vector_type(4)));

// ---- DPP plumbing (all control args compile-time) ----
#define ROW_SHR1    0x111
#define ROW_SHR2    0x112
#define ROW_SHR4    0x114
#define ROW_SHR8    0x118
#define ROW_BCAST15 0x142
#define ROW_BCAST31 0x143

template <int CTRL>
__device__ __forceinline__ float dpp0_f32(float v) {
    return __builtin_bit_cast(float, __builtin_amdgcn_update_dpp(
        0, __builtin_bit_cast(int, v), CTRL, 0xF, 0xF, true));
}

template <int CTRL>
__device__ __forceinline__ double dpp0_f64(double v) {
    union { double d; unsigned long long u; } x; x.d = v;
    int lo = (int)(unsigned int)(x.u & 0xffffffffull);
    int hi = (int)(unsigned int)(x.u >> 32);
    int olo = __builtin_amdgcn_update_dpp(0, lo, CTRL, 0xF, 0xF, true);
    int ohi = __builtin_amdgcn_update_dpp(0, hi, CTRL, 0xF, 0xF, true);
    union { unsigned long long u; double d; } y;
    y.u = ((unsigned long long)(unsigned int)ohi << 32) | (unsigned int)olo;
    return y.d;
}

__device__ __forceinline__ float wave_sum_f32(float v) {
    v += dpp0_f32<ROW_SHR1>(v);
    v += dpp0_f32<ROW_SHR2>(v);
    v += dpp0_f32<ROW_SHR4>(v);
    v += dpp0_f32<ROW_SHR8>(v);
    v += dpp0_f32<ROW_BCAST15>(v);
    v += dpp0_f32<ROW_BCAST31>(v);
    return v;                       // lane 63 holds the full wave sum
}

__device__ __forceinline__ double wave_sum_f64(double v) {
    v += dpp0_f64<ROW_SHR1>(v);
    v += dpp0_f64<ROW_SHR2>(v);
    v += dpp0_f64<ROW_SHR4>(v);
    v += dpp0_f64<ROW_SHR8>(v);
    v += dpp0_f64<ROW_BCAST15>(v);
    v += dpp0_f64<ROW_BCAST31>(v);
    return v;                       // lane 63 holds the full wave sum
}

__device__ __forceinline__ bool vi_gt(float v0, int i0, float v1, int i1) {
    // lexicographic (value desc, index asc) — matches jax.lax.top_k + stable sort
    return (v0 > v1) || (v0 == v1 && i0 < i1);
}

template <int CTRL>
__device__ __forceinline__ void t2_step(float& v1, int& i1, float& v2, int& i2) {
    const int NEGINF = 0xFF800000;       // bits of -inf
    const int BIGIDX = 0x7fffffff;
    float ov1 = __builtin_bit_cast(float, __builtin_amdgcn_update_dpp(
        NEGINF, __builtin_bit_cast(int, v1), CTRL, 0xF, 0xF, false));
    int   oi1 = __builtin_amdgcn_update_dpp(BIGIDX, i1, CTRL, 0xF, 0xF, false);
    float ov2 = __builtin_bit_cast(float, __builtin_amdgcn_update_dpp(
        NEGINF, __builtin_bit_cast(int, v2), CTRL, 0xF, 0xF, false));
    int   oi2 = __builtin_amdgcn_update_dpp(BIGIDX, i2, CTRL, 0xF, 0xF, false);
    if (vi_gt(ov1, oi1, v1, i1)) {
        float nv2; int ni2;
        if (vi_gt(v1, i1, ov2, oi2)) { nv2 = v1;  ni2 = i1; }
        else                         { nv2 = ov2; ni2 = oi2; }
        v1 = ov1; i1 = oi1; v2 = nv2; i2 = ni2;
    } else {
        if (vi_gt(ov1, oi1, v2, i2)) { v2 = ov1; i2 = oi1; }
    }
}

// ---------------------------------------------------------------------------
// 1) per-weight-row q[t] = sigma[t/2]/max(||W_t||,eps) (f64) + zero hist.
// ---------------------------------------------------------------------------
__global__ __launch_bounds__(256) void norm_kernel(
    const float* __restrict__ weights,
    const float* __restrict__ sigma,
    double* __restrict__ q,
    unsigned* __restrict__ hist,
    int P2, int nbins)
{
    const int gid = blockIdx.x * 256 + threadIdx.x;
    if (gid < nbins) hist[gid] = 0u;

    const int lane = threadIdx.x & 63;
    const int t = (blockIdx.x << 2) + (threadIdx.x >> 6);
    if (t >= P2) return;

    const vf4* wv = (const vf4*)(weights + (size_t)t * D_DIM);
    vf4 a0 = wv[lane], a1 = wv[lane + 64], a2 = wv[lane + 128];

    double n = 0.0;
#define SQ(a)                                                                  \
    n += (double)a.x * a.x + (double)a.y * a.y                                 \
       + (double)a.z * a.z + (double)a.w * a.w;
    SQ(a0) SQ(a1) SQ(a2)
#undef SQ
    n = wave_sum_f64(n);
    if (lane == 63) {
        q[t] = (double)sigma[t >> 1] / fmax(sqrt(n), EPS_N);
    }
}

// ---------------------------------------------------------------------------
// 2) per-row top-2 (one wave/row) -> pb[r] = (a<<17)|(b<<24); hist[p]++.
// ---------------------------------------------------------------------------
__global__ __launch_bounds__(256) void topk_hist_kernel(
    const float* __restrict__ first_out,
    unsigned* __restrict__ pb,
    unsigned* __restrict__ hist,
    int B)
{
    const int lane = threadIdx.x & 63;
    const int r = (blockIdx.x << 2) + (threadIdx.x >> 6);
    if (r >= B) return;

    const float* fo = first_out + (size_t)r * C_DIM;
    float e0 = fo[lane];
    int   j1 = lane + 64;
    float e1 = (j1 < C_DIM) ? fo[j1] : -INFINITY;

    float v1, v2; int i1, i2;
    if (vi_gt(e1, j1, e0, lane)) { v1 = e1; i1 = j1;   v2 = e0; i2 = lane; }
    else                         { v1 = e0; i1 = lane; v2 = e1; i2 = j1; }

    t2_step<ROW_SHR1>(v1, i1, v2, i2);
    t2_step<ROW_SHR2>(v1, i1, v2, i2);
    t2_step<ROW_SHR4>(v1, i1, v2, i2);
    t2_step<ROW_SHR8>(v1, i1, v2, i2);
    t2_step<ROW_BCAST15>(v1, i1, v2, i2);
    t2_step<ROW_BCAST31>(v1, i1, v2, i2);

    if (lane == 63) {
        const int a = min(i1, i2);
        const int b = max(i1, i2);
        const int p = b * (b - 1) / 2 + a;
        pb[r] = ((unsigned)a << 17) | ((unsigned)b << 24);
        atomicAdd(&hist[p], 1u);
    }
}

// ---------------------------------------------------------------------------
// 3) exclusive prefix sum over nbins (<= 5120), one block of 1024 threads.
// ---------------------------------------------------------------------------
#define SCAN_T 1024
#define BINS_PER_T 5
__global__ __launch_bounds__(SCAN_T) void scan_kernel(
    const unsigned* __restrict__ hist,
    unsigned* __restrict__ ofs,
    int nbins)
{
    __shared__ unsigned lds[SCAN_T];
    const int t = threadIdx.x;
    unsigned loc[BINS_PER_T];
    unsigned s = 0;
#pragma unroll
    for (int k = 0; k < BINS_PER_T; ++k) {
        int idx = t * BINS_PER_T + k;
        unsigned v = (idx < nbins) ? hist[idx] : 0u;
        loc[k] = s;                 // thread-local exclusive prefix
        s += v;
    }
    lds[t] = s;
    __syncthreads();
    for (int d = 1; d < SCAN_T; d <<= 1) {
        unsigned v = (t >= d) ? lds[t - d] : 0u;
        __syncthreads();
        lds[t] += v;
        __syncthreads();
    }
    unsigned base = (t > 0) ? lds[t - 1] : 0u;   // exclusive of this thread
#pragma unroll
    for (int k = 0; k < BINS_PER_T; ++k) {
        int idx = t * BINS_PER_T + k;
        if (idx < nbins) ofs[idx] = base + loc[k];
    }
}

// ---------------------------------------------------------------------------
// 4) scatter rows into pair-major order: perm[slot] = r | pb[r].
// ---------------------------------------------------------------------------
__global__ __launch_bounds__(256) void scatter_kernel(
    const unsigned* __restrict__ pb,
    unsigned* __restrict__ ofs,
    unsigned* __restrict__ perm,
    int B)
{
    const int r = blockIdx.x * 256 + threadIdx.x;
    if (r >= B) return;
    const unsigned v = pb[r];
    const int a = (int)((v >> 17) & 0x7f);
    const int b = (int)((v >> 24) & 0x7f);
    const int p = b * (b - 1) / 2 + a;
    const unsigned slot = atomicAdd(&ofs[p], 1u);
    perm[slot] = v | (unsigned)r;
}

// ---------------------------------------------------------------------------
// 5) main: logical wave L*4+wid -> row perm[.]; bijective XCD-chunk swizzle
//    puts each contiguous pair-sorted slice on ONE XCD, so each 6KB weight
//    tile is fetched once into that XCD's L2 and re-read at L2 speed.
// ---------------------------------------------------------------------------
__global__ __launch_bounds__(256) void mlcl_main(
    const float* __restrict__ x,
    const float* __restrict__ weights,
    const double* __restrict__ q,
    const unsigned* __restrict__ perm,
    float* __restrict__ out,
    int B, int cpx)
{
    // bijective swizzle: dispatch round-robins bid across 8 XCDs; give XCD
    // (bid&7) the logical chunk [(bid&7)*cpx, ...). cpx = nblk/8.
    int L = blockIdx.x;
    if (cpx) L = (int)(blockIdx.x & 7) * cpx + (int)(blockIdx.x >> 3);

    const int lane = threadIdx.x & 63;
    const int i = (L << 2) + (threadIdx.x >> 6);
    if (i >= B) return;

    const int e = __builtin_amdgcn_readfirstlane((int)perm[i]);
    const int r = e & 0x1ffff;
    const int a = (e >> 17) & 0x7f;
    const int b = (e >> 24) & 0x7f;
    const int p = b * (b - 1) / 2 + a;

    // uniform p -> scalar loads for q, scalar base for weights
    const double q0 = q[2 * (size_t)p];
    const double q1 = q[2 * (size_t)p + 1];

    const vf4* xv = (const vf4*)(x + (size_t)r * D_DIM);
    vf4 xa0 = xv[lane], xa1 = xv[lane + 64], xa2 = xv[lane + 128];

    const vf4* wv = (const vf4*)(weights + (size_t)p * (2 * D_DIM));
    vf4 w00 = wv[lane],       w01 = wv[lane + 64],       w02 = wv[lane + 128];
    vf4 w10 = wv[192 + lane], w11 = wv[192 + lane + 64], w12 = wv[192 + lane + 128];

    float  xx = 0.f;                 // common positive scale — f32 ok
    double d0 = 0.0, d1 = 0.0;       // feed argmax — f64
#define ACC(xa, w0, w1)                                                       \
    xx += xa.x * xa.x + xa.y * xa.y + xa.z * xa.z + xa.w * xa.w;              \
    d0 += (double)xa.x * w0.x + (double)xa.y * w0.y                           \
        + (double)xa.z * w0.z + (double)xa.w * w0.w;                          \
    d1 += (double)xa.x * w1.x + (double)xa.y * w1.y                           \
        + (double)xa.z * w1.z + (double)xa.w * w1.w;
    ACC(xa0, w00, w10)
    ACC(xa1, w01, w11)
    ACC(xa2, w02, w12)
#undef ACC

    xx = wave_sum_f32(xx);
    d0 = wave_sum_f64(d0);
    d1 = wave_sum_f64(d1);

    if (lane == 63) {
        const double inx = 1.0 / fmax(sqrt((double)xx), EPS_N);
        const double l0  = q0 * d0 * inx;
        const double l1  = q1 * d1 * inx;
        const int sel = (l1 > l0) ? 1 : 0;   // jnp.argmax: first index wins ties
        out[r] = (float)(sel ? b : a);
        float2 lg = make_float2((float)l0, (float)l1);
        *(float2*)(out + B + 2 * (size_t)r) = lg;    // 8B-aligned: B even
    }
}

extern "C" void kernel_launch(void* const* d_in, const int* in_sizes, int n_in,
                              void* d_out, int out_size, void* d_ws, size_t ws_size,
                              hipStream_t stream) {
    const float* x         = (const float*)d_in[0];
    const float* first_out = (const float*)d_in[1];
    const float* weights   = (const float*)d_in[2];
    const float* sigma     = (const float*)d_in[3];
    float* out = (float*)d_out;

    const int B  = in_sizes[0] / D_DIM;    // 65536
    const int P2 = in_sizes[2] / D_DIM;    // 2*P = 9900
    const int NB = P2 / 2;                 // 4950 pairs

    // ws layout (all 256B-aligned)
    char* ws = (char*)d_ws;
    size_t o = 0;
    double*   q    = (double*)(ws + o);  o += ((size_t)P2 * 8 + 255) & ~255ull;
    unsigned* hist = (unsigned*)(ws + o); o += ((size_t)NB * 4 + 255) & ~255ull;
    unsigned* ofs  = (unsigned*)(ws + o); o += ((size_t)NB * 4 + 255) & ~255ull;
    unsigned* pb   = (unsigned*)(ws + o); o += ((size_t)B * 4 + 255) & ~255ull;
    unsigned* perm = (unsigned*)(ws + o);

    const int nblk_main = (B + 3) / 4;
    const int cpx = (nblk_main % 8 == 0) ? nblk_main / 8 : 0;  // 0 -> identity

    hipLaunchKernelGGL(norm_kernel, dim3((P2 + 3) / 4), dim3(256), 0, stream,
                       weights, sigma, q, hist, P2, NB);
    hipLaunchKernelGGL(topk_hist_kernel, dim3((B + 3) / 4), dim3(256), 0, stream,
                       first_out, pb, hist, B);
    hipLaunchKernelGGL(scan_kernel, dim3(1), dim3(SCAN_T), 0, stream,
                       hist, ofs, NB);
    hipLaunchKernelGGL(scatter_kernel, dim3((B + 255) / 256), dim3(256), 0, stream,
                       pb, ofs, perm, B);
    hipLaunchKernelGGL(mlcl_main, dim3(nblk_main), dim3(256), 0, stream,
                       x, weights, q, perm, out, B, cpx);
}

// Round 5
// 319.261 us; speedup vs baseline: 1.0917x; 1.0917x over previous
//
#include <hip/hip_runtime.h>
#include <math.h>

// MultiLocalCosineLinear: B=65536 rows, D=768, C=100, P=4950 pairs.
// out layout (all float32): [0..B)  = preds (class id as float)
//                           [B..3B) = logits, row-major (B,2)
//
// R11: terminal revert to the best measured structure (R6/round-0, 318.4 us)
// + R8's safe x-load hoist (x loads issued before the top-2 scan; no data
// dependency, hides global-load latency under the scan).
//
// Session evidence (why this is the stopping point):
//  - fused kernel serves 633 MB in ~84 us = 7.5 TB/s aggregate, ABOVE the
//    6.3 TB/s achievable HBM rate (L3-assisted) — memory-fabric-bound.
//  - ALU cuts (R8: -50% f64 FMA, -2 reductions): no change -> not VALU-bound.
//  - pair-grouped pipeline (R9) and + XCD pinning (R10): 346/348 us — the
//    x-gather + pipeline overhead costs more than the weight-locality gain
//    (x is 6.7x the weight set; random-w is the right side of the tradeoff).
//  - remaining 234 us of the bench total is harness fills at ~86% peak HBM.

#define D_DIM 768
#define C_DIM 100
#define EPS_N 1e-12

typedef float vf4 __attribute__((ext_vector_type(4)));

// ---- DPP plumbing (all control args compile-time) ----
#define ROW_SHR1    0x111
#define ROW_SHR2    0x112
#define ROW_SHR4    0x114
#define ROW_SHR8    0x118
#define ROW_BCAST15 0x142
#define ROW_BCAST31 0x143

template <int CTRL>
__device__ __forceinline__ float dpp0_f32(float v) {
    // invalid-source lanes read 0 (bound_ctrl) — neutral for sum
    return __builtin_bit_cast(float, __builtin_amdgcn_update_dpp(
        0, __builtin_bit_cast(int, v), CTRL, 0xF, 0xF, true));
}

template <int CTRL>
__device__ __forceinline__ double dpp0_f64(double v) {
    union { double d; unsigned long long u; } x; x.d = v;
    int lo = (int)(unsigned int)(x.u & 0xffffffffull);
    int hi = (int)(unsigned int)(x.u >> 32);
    int olo = __builtin_amdgcn_update_dpp(0, lo, CTRL, 0xF, 0xF, true);
    int ohi = __builtin_amdgcn_update_dpp(0, hi, CTRL, 0xF, 0xF, true);
    union { unsigned long long u; double d; } y;
    y.u = ((unsigned long long)(unsigned int)ohi << 32) | (unsigned int)olo;
    return y.d;
}

__device__ __forceinline__ float wave_sum_f32(float v) {
    v += dpp0_f32<ROW_SHR1>(v);
    v += dpp0_f32<ROW_SHR2>(v);
    v += dpp0_f32<ROW_SHR4>(v);
    v += dpp0_f32<ROW_SHR8>(v);
    v += dpp0_f32<ROW_BCAST15>(v);
    v += dpp0_f32<ROW_BCAST31>(v);
    return v;                       // lane 63 holds the full wave sum
}

__device__ __forceinline__ double wave_sum_f64(double v) {
    v += dpp0_f64<ROW_SHR1>(v);
    v += dpp0_f64<ROW_SHR2>(v);
    v += dpp0_f64<ROW_SHR4>(v);
    v += dpp0_f64<ROW_SHR8>(v);
    v += dpp0_f64<ROW_BCAST15>(v);
    v += dpp0_f64<ROW_BCAST31>(v);
    return v;                       // lane 63 holds the full wave sum
}

__device__ __forceinline__ bool vi_gt(float v0, int i0, float v1, int i1) {
    // lexicographic (value desc, index asc) — matches jax.lax.top_k + stable sort
    return (v0 > v1) || (v0 == v1 && i0 < i1);
}

// one DPP scan step of the top-2 merge: pull partner's (v1,i1,v2,i2) via DPP
// (invalid lanes see (-inf, INT_MAX) — neutral), merge into local top-2.
template <int CTRL>
__device__ __forceinline__ void t2_step(float& v1, int& i1, float& v2, int& i2) {
    const int NEGINF = 0xFF800000;       // bits of -inf
    const int BIGIDX = 0x7fffffff;
    float ov1 = __builtin_bit_cast(float, __builtin_amdgcn_update_dpp(
        NEGINF, __builtin_bit_cast(int, v1), CTRL, 0xF, 0xF, false));
    int   oi1 = __builtin_amdgcn_update_dpp(BIGIDX, i1, CTRL, 0xF, 0xF, false);
    float ov2 = __builtin_bit_cast(float, __builtin_amdgcn_update_dpp(
        NEGINF, __builtin_bit_cast(int, v2), CTRL, 0xF, 0xF, false));
    int   oi2 = __builtin_amdgcn_update_dpp(BIGIDX, i2, CTRL, 0xF, 0xF, false);
    if (vi_gt(ov1, oi1, v1, i1)) {
        float nv2; int ni2;
        if (vi_gt(v1, i1, ov2, oi2)) { nv2 = v1;  ni2 = i1; }
        else                         { nv2 = ov2; ni2 = oi2; }
        v1 = ov1; i1 = oi1; v2 = nv2; i2 = ni2;
    } else {
        if (vi_gt(ov1, oi1, v2, i2)) { v2 = ov1; i2 = oi1; }
    }
}

__global__ __launch_bounds__(256) void mlcl_kernel(
    const float* __restrict__ x,
    const float* __restrict__ first_out,
    const float* __restrict__ weights,
    const float* __restrict__ sigma,
    float* __restrict__ out,
    int B)
{
    const int lane = threadIdx.x & 63;
    const int r = (blockIdx.x << 2) + (threadIdx.x >> 6);
    if (r >= B) return;

    // ---------- issue fo + x loads first (x has no dependency on the scan;
    // its latency hides under the top-2 scan) ----------
    const float* fo = first_out + (size_t)r * C_DIM;
    float e0 = fo[lane];
    int   j1 = lane + 64;
    float e1 = (j1 < C_DIM) ? fo[j1] : -INFINITY;

    const vf4* xv = (const vf4*)(x + (size_t)r * D_DIM);
    vf4 xa0 = xv[lane], xa1 = xv[lane + 64], xa2 = xv[lane + 128];

    // ---------- top-2 of first_out[r, 0:100] via DPP scan ----------
    float v1, v2; int i1, i2;
    if (vi_gt(e1, j1, e0, lane)) { v1 = e1; i1 = j1;   v2 = e0; i2 = lane; }
    else                         { v1 = e0; i1 = lane; v2 = e1; i2 = j1; }

    t2_step<ROW_SHR1>(v1, i1, v2, i2);
    t2_step<ROW_SHR2>(v1, i1, v2, i2);
    t2_step<ROW_SHR4>(v1, i1, v2, i2);
    t2_step<ROW_SHR8>(v1, i1, v2, i2);
    t2_step<ROW_BCAST15>(v1, i1, v2, i2);
    t2_step<ROW_BCAST31>(v1, i1, v2, i2);
    // lane 63 holds the global top-2; broadcast via readlane (SGPR, uniform)
    const int gi1 = __builtin_amdgcn_readlane(i1, 63);
    const int gi2 = __builtin_amdgcn_readlane(i2, 63);
    const int a = min(gi1, gi2);
    const int b = max(gi1, gi2);
    const int p = b * (b - 1) / 2 + a;

    // prefetch sigma (uniform p -> scalar load), hides under the dot loop
    const float sig = sigma[p];

    // ---------- dots + norms over D=768 ----------
    const vf4* wv = (const vf4*)(weights + (size_t)p * (2 * D_DIM));
    vf4 w00 = wv[lane],       w01 = wv[lane + 64],       w02 = wv[lane + 128];
    vf4 w10 = wv[192 + lane], w11 = wv[192 + lane + 64], w12 = wv[192 + lane + 128];

    float  xx = 0.f;                                  // common positive scale — f32 ok
    double d0 = 0.0, d1 = 0.0, n0 = 0.0, n1 = 0.0;    // feed argmax — f64
#define ACC(xa, w0, w1)                                                       \
    xx += xa.x * xa.x + xa.y * xa.y + xa.z * xa.z + xa.w * xa.w;              \
    d0 += (double)xa.x * w0.x + (double)xa.y * w0.y                           \
        + (double)xa.z * w0.z + (double)xa.w * w0.w;                          \
    d1 += (double)xa.x * w1.x + (double)xa.y * w1.y                           \
        + (double)xa.z * w1.z + (double)xa.w * w1.w;                          \
    n0 += (double)w0.x * w0.x + (double)w0.y * w0.y                           \
        + (double)w0.z * w0.z + (double)w0.w * w0.w;                          \
    n1 += (double)w1.x * w1.x + (double)w1.y * w1.y                           \
        + (double)w1.z * w1.z + (double)w1.w * w1.w;
    ACC(xa0, w00, w10)
    ACC(xa1, w01, w11)
    ACC(xa2, w02, w12)
#undef ACC

    xx = wave_sum_f32(xx);
    d0 = wave_sum_f64(d0);
    d1 = wave_sum_f64(d1);
    n0 = wave_sum_f64(n0);
    n1 = wave_sum_f64(n1);

    // ---------- epilogue on lane 63 (holds the sums) ----------
    if (lane == 63) {
        const double s   = (double)sig;
        const double inx = s / fmax(sqrt((double)xx), EPS_N);
        const double l0  = inx * d0 / fmax(sqrt(n0), EPS_N);
        const double l1  = inx * d1 / fmax(sqrt(n1), EPS_N);
        const int sel = (l1 > l0) ? 1 : 0;   // jnp.argmax: first index wins ties
        out[r] = (float)(sel ? b : a);
        float2 lg = make_float2((float)l0, (float)l1);
        *(float2*)(out + B + 2 * (size_t)r) = lg;    // 8B-aligned: B even
    }
}

extern "C" void kernel_launch(void* const* d_in, const int* in_sizes, int n_in,
                              void* d_out, int out_size, void* d_ws, size_t ws_size,
                              hipStream_t stream) {
    const float* x         = (const float*)d_in[0];
    const float* first_out = (const float*)d_in[1];
    const float* weights   = (const float*)d_in[2];
    const float* sigma     = (const float*)d_in[3];
    float* out = (float*)d_out;

    const int B = in_sizes[0] / D_DIM;     // 65536
    hipLaunchKernelGGL(mlcl_kernel, dim3((B + 3) / 4), dim3(256), 0, stream,
                       x, first_out, weights, sigma, out, B);
}